// Round 3
// baseline (1095.980 us; speedup 1.0000x reference)
//
#include <hip/hip_runtime.h>
#include <hip/hip_bf16.h>
#include <stdint.h>

// LSTM fused cell, MI355X gfx950 — single kernel, fp32-direct staging.
// out = [x|h] @ [W_ih|W_hh]^T + b ; gates f,i,s,o ; c' = f*c + i*s ; h' = o*tanh(c')
// fp32 operands are staged to LDS as-is (4B/elem == bf16 hi+lo 2+2B), then split
// hi/lo in registers and fed to 3-pass bf16 MFMA (hi*hi + hi*lo + lo*hi), fp32 acc.
// R3: removed pack kernels entirely (was ~220us round-trip). Same swizzle idea as
// R2 adapted to 16 16B-groups/row: slot = kg ^ (row&15); gload_lds dest linear
// (rule 21), source k-group pre-swizzled per-thread.

typedef float  f32x4  __attribute__((ext_vector_type(4)));
typedef __bf16 bf16x8 __attribute__((ext_vector_type(8)));

#define B_ROWS 4096
#define HDIM   2048
#define KDIM   4096               // I + H
#define BH     ((size_t)B_ROWS * HDIM)

__device__ __forceinline__ void async16f(const float* g, float* s) {
    __builtin_amdgcn_global_load_lds(
        (const __attribute__((address_space(1))) unsigned int*)g,
        (__attribute__((address_space(3))) unsigned int*)s, 16, 0, 0);
}

__device__ __forceinline__ float sigmoid_f(float x) {
    return 1.0f / (1.0f + __expf(-x));
}
__device__ __forceinline__ float tanh_f(float x) {
    float t = __expf(-2.0f * fabsf(x));
    return copysignf((1.0f - t) / (1.0f + t), x);
}

// Block tile: 128 B-rows x (32 h-cols * 4 gates = 128 W-rows), BK=64, fp32 LDS.
// 4 waves 2x2; wave's 4 N-fragments = the 4 gates of 16 h-cols (register-local
// epilogue). LDS rows are 64 f32 = 16 groups of 16B; group slot s of row j holds
// global k-group s ^ (j&15)  => ds_read_b128 column reads are 2-way aliased
// (wave64 minimum, free per m136).
__global__ __launch_bounds__(256, 2) void lstm_fused_kernel(
    const float* __restrict__ x,   const float* __restrict__ h,
    const float* __restrict__ wih, const float* __restrict__ whh,
    const float* __restrict__ bias, const float* __restrict__ cin,
    float* __restrict__ out)
{
    __shared__ __align__(16) float sA[128 * 64];
    __shared__ __align__(16) float sW[128 * 64];

    const int tid  = threadIdx.x;
    const int wid  = tid >> 6;
    const int lane = tid & 63;
    const int wm   = wid >> 1;
    const int wn   = wid & 1;
    const int row0  = blockIdx.y * 128;   // batch rows
    const int hcol0 = blockIdx.x * 32;    // h columns

    // Staging geometry: thread t covers (row stripe lrow = t>>4, 16B slot = t&15);
    // round r adds 16 rows. Wave-linear LDS dest: off = wid*1024 + lane*16 (+r*4096) B.
    const int lrow = tid >> 4;            // 0..15
    const int slot = tid & 15;
    const int sw4  = ((slot ^ lrow) & 15) << 2;  // pre-swizzled source k-offset (f32)

    f32x4 acc[4][4];
#pragma unroll
    for (int m = 0; m < 4; ++m)
#pragma unroll
        for (int n = 0; n < 4; ++n)
            acc[m][n] = (f32x4)0.0f;

    const int arow = (wm << 6) + (lane & 15);
    const int brow = (wn << 6) + (lane & 15);
    const int r15  = lane & 15;

    for (int k0 = 0; k0 < KDIM; k0 += 64) {
        // k-chunks never straddle the x|h / wih|whh seam (2048 % 64 == 0).
        const float* Asrc = (k0 < 2048) ? x   : h;
        const float* Wsrc = (k0 < 2048) ? wih : whh;
        const int kc = (k0 & 2047) + sw4;
#pragma unroll
        for (int r = 0; r < 8; ++r) {
            // A: local row j = lrow + 16r  <-> global batch row row0 + j
            async16f(Asrc + (size_t)(row0 + lrow + 16 * r) * 2048 + kc,
                     &sA[(lrow + 16 * r) * 64 + (slot << 2)]);
            // W: local row j -> W row = gate(j)*2048 + hcol0 + (j>>6)*16 + (j&15)
            //    with j = lrow + 16r: gate = r&3, j>>6 = r>>2, j&15 = lrow
            const int wrow = ((r & 3) << 11) + hcol0 + ((r >> 2) << 4) + lrow;
            async16f(Wsrc + (size_t)wrow * 2048 + kc,
                     &sW[(lrow + 16 * r) * 64 + (slot << 2)]);
        }
        __syncthreads();   // compiler emits vmcnt(0) drain before barrier

#pragma unroll
        for (int kk = 0; kk < 64; kk += 32) {
            const int kg0 = (kk >> 2) + ((lane >> 4) << 1);  // even k-group
            const int s0  = ((kg0 ^ r15) << 2);              // f32 elem offsets
            const int s1  = (((kg0 + 1) ^ r15) << 2);
            bf16x8 ah[4], alo[4], bh[4], blo[4];
#pragma unroll
            for (int m = 0; m < 4; ++m) {
                const float* base = &sA[(arow + m * 16) * 64];
                f32x4 f0 = *reinterpret_cast<const f32x4*>(base + s0);
                f32x4 f1 = *reinterpret_cast<const f32x4*>(base + s1);
#pragma unroll
                for (int j = 0; j < 4; ++j) {
                    __bf16 h0 = (__bf16)f0[j];
                    ah[m][j]     = h0;
                    alo[m][j]    = (__bf16)(f0[j] - (float)h0);
                    __bf16 h1 = (__bf16)f1[j];
                    ah[m][4 + j]  = h1;
                    alo[m][4 + j] = (__bf16)(f1[j] - (float)h1);
                }
            }
#pragma unroll
            for (int n = 0; n < 4; ++n) {
                const float* base = &sW[(brow + n * 16) * 64];
                f32x4 f0 = *reinterpret_cast<const f32x4*>(base + s0);
                f32x4 f1 = *reinterpret_cast<const f32x4*>(base + s1);
#pragma unroll
                for (int j = 0; j < 4; ++j) {
                    __bf16 h0 = (__bf16)f0[j];
                    bh[n][j]     = h0;
                    blo[n][j]    = (__bf16)(f0[j] - (float)h0);
                    __bf16 h1 = (__bf16)f1[j];
                    bh[n][4 + j]  = h1;
                    blo[n][4 + j] = (__bf16)(f1[j] - (float)h1);
                }
            }
            // pass 1: hi*hi
#pragma unroll
            for (int m = 0; m < 4; ++m)
#pragma unroll
                for (int n = 0; n < 4; ++n)
                    acc[m][n] = __builtin_amdgcn_mfma_f32_16x16x32_bf16(ah[m], bh[n], acc[m][n], 0, 0, 0);
            // pass 2: hi*lo
#pragma unroll
            for (int m = 0; m < 4; ++m)
#pragma unroll
                for (int n = 0; n < 4; ++n)
                    acc[m][n] = __builtin_amdgcn_mfma_f32_16x16x32_bf16(ah[m], blo[n], acc[m][n], 0, 0, 0);
            // pass 3: lo*hi
#pragma unroll
            for (int m = 0; m < 4; ++m)
#pragma unroll
                for (int n = 0; n < 4; ++n)
                    acc[m][n] = __builtin_amdgcn_mfma_f32_16x16x32_bf16(alo[m], bh[n], acc[m][n], 0, 0, 0);
        }
        __syncthreads();
    }

    // Epilogue: per lane, acc[m][gate][r] are the 4 gate pre-activations of
    // (row = row0+wm*64+m*16+(lane>>4)*4+r, hcol = hcol0+wn*16+(lane&15)).
    const int hcol = hcol0 + (wn << 4) + (lane & 15);
    const float bf_ = bias[hcol];
    const float bi_ = bias[HDIM + hcol];
    const float bs_ = bias[2 * HDIM + hcol];
    const float bo_ = bias[3 * HDIM + hcol];
    const int rbase = row0 + (wm << 6) + ((lane >> 4) << 2);
#pragma unroll
    for (int m = 0; m < 4; ++m) {
#pragma unroll
        for (int r = 0; r < 4; ++r) {
            int grow = rbase + m * 16 + r;
            float gf = sigmoid_f(acc[m][0][r] + bf_);
            float gi = sigmoid_f(acc[m][1][r] + bi_);
            float gs = tanh_f   (acc[m][2][r] + bs_);
            float go = sigmoid_f(acc[m][3][r] + bo_);
            size_t o0 = (size_t)grow * HDIM + hcol;
            float cn = gf * cin[o0] + gi * gs;
            float hn = go * tanh_f(cn);
            out[o0]          = hn;
            out[BH + o0]     = cn;
            out[2 * BH + o0] = go;
        }
    }
}

extern "C" void kernel_launch(void* const* d_in, const int* in_sizes, int n_in,
                              void* d_out, int out_size, void* d_ws, size_t ws_size,
                              hipStream_t stream) {
    const float* x    = (const float*)d_in[0];
    const float* h    = (const float*)d_in[1];
    const float* c    = (const float*)d_in[2];
    // d_in[3] ("o") is unused by the reference computation.
    const float* w_ih = (const float*)d_in[4];
    const float* w_hh = (const float*)d_in[5];
    const float* b    = (const float*)d_in[6];
    float* out = (float*)d_out;

    dim3 grid(HDIM / 32, B_ROWS / 128);  // (64, 32)
    lstm_fused_kernel<<<grid, 256, 0, stream>>>(x, h, w_ih, w_hh, b, c, out);
}